// Round 6
// baseline (260.689 us; speedup 1.0000x reference)
//
#include <hip/hip_runtime.h>
#include <hip/hip_cooperative_groups.h>
#include <hip/hip_bf16.h>
#include <math.h>

namespace cg = cooperative_groups;

#define B_ 8
#define L_ 256
#define E_ 256
#define H_ 8
#define A_ 32

typedef __attribute__((ext_vector_type(8))) short bf16x8;
typedef __attribute__((ext_vector_type(4))) float f32x4;

// LDS layout (byte offsets into smem, total 93312 B, all 16B-aligned):
//   gemm phase : Ah 0..8192 | Al ..16384 | Bh ..24576 | Bl ..32768
//   attn phase : Qt[32][260] f32 @0 (33280) | KT[32][264] bf16 @33280 (16896)
//                Kr[64][36] f32 @50176 (9216) | S[64][264] bf16 @59392 (33792)
//                wsh[32] f32 @93184 (128)
#define SMEM_BYTES 93312

// Swizzled byte offset in a [64 rows][64 bf16] tile (128 B rows): XOR the
// 16B-slot index with (row&7) -> conflict-free ds_read_b128 frag fetches.
__device__ __forceinline__ int swz(int row, int slot) {
  return row * 128 + ((slot ^ (row & 7)) << 4);
}

__device__ __forceinline__ void pack8(const float4& x, const float4& y,
                                      bf16x8& h, bf16x8& l) {
  float v[8] = {x.x, x.y, x.z, x.w, y.x, y.y, y.z, y.w};
  union { __hip_bfloat16 b[8]; bf16x8 v; } uh, ul;
#pragma unroll
  for (int i = 0; i < 8; ++i) {
    uh.b[i] = __float2bfloat16(v[i]);
    ul.b[i] = __float2bfloat16(v[i] - __bfloat162float(uh.b[i]));
  }
  h = uh.v;
  l = ul.v;
}

// ---------------------------------------------------------------------------
// NT GEMM phase body (512 thr / 8 waves; tile 64x64; wave quadrant 32x16).
// C = Ah*Bh + Ah*Bl + Al*Bh  (hi/lo compensated bf16 ~ fp32 accuracy).
// MODE 0: C0[M*N].  MODE 1: scatter to q (C0) / k (C1) in (b,h,l,a).
// ---------------------------------------------------------------------------
template <int MODE>
__device__ void gemm_body(char* lds, const float* __restrict__ Ag,
                          const float* __restrict__ Bg, float* __restrict__ C0,
                          float* __restrict__ C1, int N, int bid) {
  char* Ah = lds;
  char* Al = lds + 8192;
  char* Bh = lds + 16384;
  char* Bl = lds + 24576;

  const int ntile = N >> 6;
  const int mt = bid / ntile;
  const int nt = bid % ntile;
  const int t = threadIdx.x;
  const int wave = t >> 6, lane = t & 63;
  const int wr = wave >> 2, wc = wave & 3;  // 2x4 wave grid -> 32x16 quadrant
  const int r15 = lane & 15, g4 = lane >> 4;
  const int srow = t >> 3, slot = t & 7;    // staging: 64 rows x 8 slots

  f32x4 acc[2];
  acc[0] = (f32x4){0.f, 0.f, 0.f, 0.f};
  acc[1] = (f32x4){0.f, 0.f, 0.f, 0.f};

  for (int kt = 0; kt < 256; kt += 64) {
    const float4* ap4 =
        (const float4*)(Ag + (mt * 64 + srow) * 256 + kt + slot * 8);
    const float4* bp4 =
        (const float4*)(Bg + (nt * 64 + srow) * 256 + kt + slot * 8);
    float4 a0 = ap4[0], a1 = ap4[1];
    float4 b0 = bp4[0], b1 = bp4[1];
    bf16x8 h, l;
    pack8(a0, a1, h, l);
    *(bf16x8*)(Ah + swz(srow, slot)) = h;
    *(bf16x8*)(Al + swz(srow, slot)) = l;
    pack8(b0, b1, h, l);
    *(bf16x8*)(Bh + swz(srow, slot)) = h;
    *(bf16x8*)(Bl + swz(srow, slot)) = l;
    __syncthreads();

    bf16x8 fah[2][2], fal[2][2], fbh[2], fbl[2];
#pragma unroll
    for (int ks = 0; ks < 2; ++ks) {
      int sl = 4 * ks + g4;
#pragma unroll
      for (int rb = 0; rb < 2; ++rb) {
        int arow = wr * 32 + rb * 16 + r15;
        fah[rb][ks] = *(const bf16x8*)(Ah + swz(arow, sl));
        fal[rb][ks] = *(const bf16x8*)(Al + swz(arow, sl));
      }
      int brow = wc * 16 + r15;
      fbh[ks] = *(const bf16x8*)(Bh + swz(brow, sl));
      fbl[ks] = *(const bf16x8*)(Bl + swz(brow, sl));
    }
#pragma unroll
    for (int rb = 0; rb < 2; ++rb)
#pragma unroll
      for (int ks = 0; ks < 2; ++ks) {
        acc[rb] = __builtin_amdgcn_mfma_f32_16x16x32_bf16(fal[rb][ks], fbh[ks],
                                                          acc[rb], 0, 0, 0);
        acc[rb] = __builtin_amdgcn_mfma_f32_16x16x32_bf16(fah[rb][ks], fbl[ks],
                                                          acc[rb], 0, 0, 0);
        acc[rb] = __builtin_amdgcn_mfma_f32_16x16x32_bf16(fah[rb][ks], fbh[ks],
                                                          acc[rb], 0, 0, 0);
      }
    __syncthreads();
  }

  // epilogue (C/D layout: col = lane&15, row = (lane>>4)*4 + reg)
#pragma unroll
  for (int rb = 0; rb < 2; ++rb)
#pragma unroll
    for (int g = 0; g < 4; ++g) {
      int gr = mt * 64 + wr * 32 + rb * 16 + g4 * 4 + g;
      int gc = nt * 64 + wc * 16 + r15;
      if (MODE == 0) {
        C0[gr * N + gc] = acc[rb][g];
      } else {
        int b = gr >> 8, lrow = gr & 255;
        int hh = gc >> 6, x = gc & 63;
        float* dst = (x < A_) ? C0 : C1;
        dst[((b * H_ + hh) * L_ + lrow) * A_ + (x & 31)] = acc[rb][g];
      }
    }
}

// ---------------------------------------------------------------------------
// Attention phase body: block = (b,h) x 64-row i-tile; 8 waves x 8 rows.
// scores[i,j] = 0.6*(ck[i]+cq[j]) + 0.4*sum_a w_a*|k[i,a]+q[j,a]|
// masked softmax over j; PV (probs @ K) via bf16 MFMA (8 waves = 4 i-quads
// x 2 a-quads of the 64x32 output).
// ---------------------------------------------------------------------------
__device__ void attn_body(char* smem, const float* __restrict__ q,
                          const float* __restrict__ k,
                          const int* __restrict__ adj,
                          const float* __restrict__ w_attn,
                          float* __restrict__ vals, int bid) {
  float(*Qt)[260] = (float(*)[260])smem;
  __hip_bfloat16(*KT)[264] = (__hip_bfloat16(*)[264])(smem + 33280);
  float(*Kr)[36] = (float(*)[36])(smem + 50176);
  __hip_bfloat16(*S)[264] = (__hip_bfloat16(*)[264])(smem + 59392);
  float* wsh = (float*)(smem + 93184);

  const int bh = bid >> 2;  // 4 i-tiles of 64 rows
  const int it = bid & 3;
  const int b = bh >> 3, h = bh & 7;
  const int t = threadIdx.x;

  const float4* qb4 = (const float4*)(q + bh * (L_ * A_));
  const float4* kb4 = (const float4*)(k + bh * (L_ * A_));
#pragma unroll
  for (int r = 0; r < 4; ++r) {
    int idx4 = r * 512 + t;  // 0..2047
    int j = idx4 >> 3, ab = idx4 & 7;
    float4 v = qb4[idx4];
    Qt[ab * 4 + 0][j] = v.x;
    Qt[ab * 4 + 1][j] = v.y;
    Qt[ab * 4 + 2][j] = v.z;
    Qt[ab * 4 + 3][j] = v.w;
    float4 u = kb4[idx4];
    KT[ab * 4 + 0][j] = __float2bfloat16(u.x);
    KT[ab * 4 + 1][j] = __float2bfloat16(u.y);
    KT[ab * 4 + 2][j] = __float2bfloat16(u.z);
    KT[ab * 4 + 3][j] = __float2bfloat16(u.w);
  }
  {
    const float4* kr4g = (const float4*)(k + bh * (L_ * A_) + it * 64 * A_);
    int ii = t >> 3, ab = t & 7;  // 512 threads: 64 rows x 8 quads
    float4 v = kr4g[t];
    Kr[ii][ab * 4 + 0] = v.x;
    Kr[ii][ab * 4 + 1] = v.y;
    Kr[ii][ab * 4 + 2] = v.z;
    Kr[ii][ab * 4 + 3] = v.w;
  }
  if (t < A_) wsh[t] = w_attn[t];
  __syncthreads();

  const int wave = t >> 6, lane = t & 63;
  const int w8 = wave * 8;
  const int i0 = it * 64 + w8;
  const int* adjb = adj + b * (L_ * L_);

  int adjv[8][4];
#pragma unroll
  for (int r = 0; r < 8; ++r)
#pragma unroll
    for (int c = 0; c < 4; ++c)
      adjv[r][c] = adjb[(i0 + r) * L_ + c * 64 + lane];

  float p[8][4] = {};
  float ck[8] = {};
  float cq[4] = {};
#pragma unroll 2
  for (int ab = 0; ab < 8; ++ab) {
    float4 wv = *(const float4*)&wsh[ab * 4];
    float4 kr4[8];
#pragma unroll
    for (int r = 0; r < 8; ++r)
      kr4[r] = *(const float4*)&Kr[w8 + r][ab * 4];
#pragma unroll
    for (int r = 0; r < 8; ++r) {
      ck[r] = fmaf(wv.x, kr4[r].x, ck[r]);
      ck[r] = fmaf(wv.y, kr4[r].y, ck[r]);
      ck[r] = fmaf(wv.z, kr4[r].z, ck[r]);
      ck[r] = fmaf(wv.w, kr4[r].w, ck[r]);
    }
#pragma unroll
    for (int c = 0; c < 4; ++c) {
      const int j = c * 64 + lane;
      float q0 = Qt[ab * 4 + 0][j];
      float q1 = Qt[ab * 4 + 1][j];
      float q2 = Qt[ab * 4 + 2][j];
      float q3 = Qt[ab * 4 + 3][j];
      cq[c] = fmaf(wv.x, q0, cq[c]);
      cq[c] = fmaf(wv.y, q1, cq[c]);
      cq[c] = fmaf(wv.z, q2, cq[c]);
      cq[c] = fmaf(wv.w, q3, cq[c]);
#pragma unroll
      for (int r = 0; r < 8; ++r) {
        p[r][c] = fmaf(wv.x, fabsf(kr4[r].x + q0), p[r][c]);
        p[r][c] = fmaf(wv.y, fabsf(kr4[r].y + q1), p[r][c]);
        p[r][c] = fmaf(wv.z, fabsf(kr4[r].z + q2), p[r][c]);
        p[r][c] = fmaf(wv.w, fabsf(kr4[r].w + q3), p[r][c]);
      }
    }
  }

#pragma unroll
  for (int r = 0; r < 8; ++r) {
    float s[4];
    float m = -3.0e38f;
#pragma unroll
    for (int c = 0; c < 4; ++c) {
      float sc = fmaf(0.4f, p[r][c], 0.6f * (ck[r] + cq[c]));
      s[c] = adjv[r][c] ? sc : -3.0e38f;
      m = fmaxf(m, s[c]);
    }
#pragma unroll
    for (int off = 32; off >= 1; off >>= 1) m = fmaxf(m, __shfl_xor(m, off));
    float sum = 0.f;
#pragma unroll
    for (int c = 0; c < 4; ++c) {
      s[c] = __expf(s[c] - m);
      sum += s[c];
    }
#pragma unroll
    for (int off = 32; off >= 1; off >>= 1) sum += __shfl_xor(sum, off);
    float inv = 1.0f / sum;
#pragma unroll
    for (int c = 0; c < 4; ++c)
      S[w8 + r][c * 64 + lane] = __float2bfloat16(s[c] * inv);
  }
  __syncthreads();

  // PV: 8 waves = 4 i-quadrants x 2 a-quadrants of the 64x32 output
  const int mi = wave >> 1;
  const int ai = wave & 1;
  const int fr = lane & 15;
  const int fk = (lane >> 4) * 8;
  f32x4 acc = {0.f, 0.f, 0.f, 0.f};
#pragma unroll
  for (int kt = 0; kt < 8; ++kt) {
    bf16x8 afrag = *(const bf16x8*)&S[mi * 16 + fr][kt * 32 + fk];
    bf16x8 bfrag = *(const bf16x8*)&KT[ai * 16 + fr][kt * 32 + fk];
    acc = __builtin_amdgcn_mfma_f32_16x16x32_bf16(afrag, bfrag, acc, 0, 0, 0);
  }
  const int arow = ai * 16 + fr;
  const int rbase = mi * 16 + ((lane >> 4) << 2);
#pragma unroll
  for (int g = 0; g < 4; ++g) {
    int i = it * 64 + rbase + g;
    vals[(b * L_ + i) * E_ + h * A_ + arow] = acc[g];
  }
}

// ---------------------------------------------------------------------------
// Fused cooperative kernel: gemm1 -> grid.sync -> attn -> grid.sync -> gemm2
// ---------------------------------------------------------------------------
__global__ __launch_bounds__(512, 1) void gat_fused(
    const float* __restrict__ emb, const int* __restrict__ adj,
    const float* __restrict__ W_qk, const float* __restrict__ w_attn,
    const float* __restrict__ W_out, float* __restrict__ out,
    float* __restrict__ q, float* __restrict__ k, float* __restrict__ vals) {
  __shared__ __align__(16) char smem[SMEM_BYTES];
  cg::grid_group grid = cg::this_grid();
  const int bid = blockIdx.x;

  // phase 1: qk = emb @ W_qk^T -> q,k   (M=2048, N=512: 32x8 = 256 tiles)
  gemm_body<1>(smem, emb, W_qk, q, k, 512, bid);
  __threadfence();
  grid.sync();

  // phase 2: attention (64 bh x 4 i-tiles = 256 blocks)
  attn_body(smem, q, k, adj, w_attn, vals, bid);
  __threadfence();
  grid.sync();

  // phase 3: out = vals @ W_out^T  (M=2048, N=256: 32x4 = 128 tiles)
  if (bid < 128) gemm_body<0>(smem, vals, W_out, out, nullptr, 256, bid);
}

extern "C" void kernel_launch(void* const* d_in, const int* in_sizes, int n_in,
                              void* d_out, int out_size, void* d_ws,
                              size_t ws_size, hipStream_t stream) {
  const float* emb = (const float*)d_in[0];
  const int* adj = (const int*)d_in[1];
  const float* W_qk = (const float*)d_in[2];
  const float* w_attn = (const float*)d_in[3];
  const float* W_out = (const float*)d_in[4];
  float* out = (float*)d_out;

  float* q = (float*)d_ws;
  float* k = q + B_ * H_ * L_ * A_;
  float* vals = k + B_ * H_ * L_ * A_;

  void* args[] = {(void*)&emb, (void*)&adj,   (void*)&W_qk,
                  (void*)&w_attn, (void*)&W_out, (void*)&out,
                  (void*)&q,   (void*)&k,     (void*)&vals};
  hipLaunchCooperativeKernel((void*)gat_fused, dim3(256), dim3(512), args, 0,
                             stream);
}

// Round 7
// 97.913 us; speedup vs baseline: 2.6625x; 2.6625x over previous
//
#include <hip/hip_runtime.h>
#include <hip/hip_bf16.h>
#include <math.h>

#define B_ 8
#define L_ 256
#define E_ 256
#define H_ 8
#define A_ 32

typedef __attribute__((ext_vector_type(8))) short bf16x8;
typedef __attribute__((ext_vector_type(4))) float f32x4;

// ---------------------------------------------------------------------------
// Swizzled byte offset inside a [64 rows][64 bf16] LDS tile (128 B rows).
// XOR of the 16B-slot index with (row&7) spreads the 16-rows-same-slot
// ds_read_b128 frag fetch across all 32 banks (else 16-way conflict).
// ---------------------------------------------------------------------------
__device__ __forceinline__ int swz(int row, int slot) {
  return row * 128 + ((slot ^ (row & 7)) << 4);
}

__device__ __forceinline__ void pack8(const float4& x, const float4& y,
                                      bf16x8& h, bf16x8& l) {
  float v[8] = {x.x, x.y, x.z, x.w, y.x, y.y, y.z, y.w};
  union { __hip_bfloat16 b[8]; bf16x8 v; } uh, ul;
#pragma unroll
  for (int i = 0; i < 8; ++i) {
    uh.b[i] = __float2bfloat16(v[i]);
    ul.b[i] = __float2bfloat16(v[i] - __bfloat162float(uh.b[i]));
  }
  h = uh.v;
  l = ul.v;
}

// ---------------------------------------------------------------------------
// NT GEMM via bf16 MFMA with hi/lo compensation (fp32-grade accuracy):
//   C = Ah*Bh + Ah*Bl + Al*Bh   (error ~2^-18 relative)
// C[M,N] = A[M,K=256] * B[N,K=256]^T.
// MODE 0: C0[M*N].  MODE 1: scatter to q (C0) / k (C1) in (b,h,l,a).
// Block: 256 thr / 4 waves; tile 64x64; wave quadrant 32x32 = 2x2 frags.
// (R5-verified: passed absmax 3.9e-3; do not fuse — grid.sync costs ~80 µs.)
// ---------------------------------------------------------------------------
template <int MODE>
__global__ __launch_bounds__(256) void gemm_mfma(const float* __restrict__ Ag,
                                                 const float* __restrict__ Bg,
                                                 float* __restrict__ C0,
                                                 float* __restrict__ C1,
                                                 int N) {
  __shared__ __align__(16) char lds[4 * 8192];  // Ah | Al | Bh | Bl
  char* Ah = lds;
  char* Al = lds + 8192;
  char* Bh = lds + 16384;
  char* Bl = lds + 24576;

  const int ntile = N >> 6;
  const int mt = blockIdx.x / ntile;
  const int nt = blockIdx.x % ntile;
  const int t = threadIdx.x;
  const int wave = t >> 6, lane = t & 63;
  const int wr = wave >> 1, wc = wave & 1;
  const int r15 = lane & 15, g4 = lane >> 4;
  const int srow = t >> 2, sq = t & 3;  // staging: row 0..63, 16-col quad

  f32x4 acc[2][2];
#pragma unroll
  for (int rb = 0; rb < 2; ++rb)
#pragma unroll
    for (int cb = 0; cb < 2; ++cb) acc[rb][cb] = (f32x4){0.f, 0.f, 0.f, 0.f};

  for (int kt = 0; kt < 256; kt += 64) {
    const float4* ap4 =
        (const float4*)(Ag + (mt * 64 + srow) * 256 + kt + sq * 16);
    const float4* bp4 =
        (const float4*)(Bg + (nt * 64 + srow) * 256 + kt + sq * 16);
    float4 a0 = ap4[0], a1 = ap4[1], a2 = ap4[2], a3 = ap4[3];
    float4 b0 = bp4[0], b1 = bp4[1], b2 = bp4[2], b3 = bp4[3];
    bf16x8 h, l;
    pack8(a0, a1, h, l);
    *(bf16x8*)(Ah + swz(srow, 2 * sq)) = h;
    *(bf16x8*)(Al + swz(srow, 2 * sq)) = l;
    pack8(a2, a3, h, l);
    *(bf16x8*)(Ah + swz(srow, 2 * sq + 1)) = h;
    *(bf16x8*)(Al + swz(srow, 2 * sq + 1)) = l;
    pack8(b0, b1, h, l);
    *(bf16x8*)(Bh + swz(srow, 2 * sq)) = h;
    *(bf16x8*)(Bl + swz(srow, 2 * sq)) = l;
    pack8(b2, b3, h, l);
    *(bf16x8*)(Bh + swz(srow, 2 * sq + 1)) = h;
    *(bf16x8*)(Bl + swz(srow, 2 * sq + 1)) = l;
    __syncthreads();

    bf16x8 fah[2][2], fal[2][2], fbh[2][2], fbl[2][2];
#pragma unroll
    for (int rb = 0; rb < 2; ++rb)
#pragma unroll
      for (int ks = 0; ks < 2; ++ks) {
        int slot = 4 * ks + g4;
        int arow = wr * 32 + rb * 16 + r15;
        fah[rb][ks] = *(const bf16x8*)(Ah + swz(arow, slot));
        fal[rb][ks] = *(const bf16x8*)(Al + swz(arow, slot));
        int brow = wc * 32 + rb * 16 + r15;
        fbh[rb][ks] = *(const bf16x8*)(Bh + swz(brow, slot));
        fbl[rb][ks] = *(const bf16x8*)(Bl + swz(brow, slot));
      }
#pragma unroll
    for (int rb = 0; rb < 2; ++rb)
#pragma unroll
      for (int cb = 0; cb < 2; ++cb)
#pragma unroll
        for (int ks = 0; ks < 2; ++ks) {
          acc[rb][cb] = __builtin_amdgcn_mfma_f32_16x16x32_bf16(
              fal[rb][ks], fbh[cb][ks], acc[rb][cb], 0, 0, 0);
          acc[rb][cb] = __builtin_amdgcn_mfma_f32_16x16x32_bf16(
              fah[rb][ks], fbl[cb][ks], acc[rb][cb], 0, 0, 0);
          acc[rb][cb] = __builtin_amdgcn_mfma_f32_16x16x32_bf16(
              fah[rb][ks], fbh[cb][ks], acc[rb][cb], 0, 0, 0);
        }
    __syncthreads();
  }

  // epilogue (C/D layout m89: col=lane&15, row=(lane>>4)*4+reg)
#pragma unroll
  for (int rb = 0; rb < 2; ++rb)
#pragma unroll
    for (int cb = 0; cb < 2; ++cb)
#pragma unroll
      for (int g = 0; g < 4; ++g) {
        int gr = mt * 64 + wr * 32 + rb * 16 + g4 * 4 + g;
        int gc = nt * 64 + wc * 32 + cb * 16 + r15;
        if (MODE == 0) {
          C0[gr * N + gc] = acc[rb][cb][g];
        } else {
          int b = gr >> 8, lrow = gr & 255;
          int x = gc & 63;                       // h = nt (N=512)
          float* dst = (x < A_) ? C0 : C1;
          dst[((b * H_ + nt) * L_ + lrow) * A_ + (x & 31)] = acc[rb][cb][g];
        }
      }
}

// ---------------------------------------------------------------------------
// Attention: block = (b,h) x 64-row i-tile, 512 thr / 8 waves x 8 rows.
// (R6-verified math; standalone kernel -> staging redundancy halved vs R5.)
// scores[i,j] = 0.6*(ck[i]+cq[j]) + 0.4*sum_a w_a*|k[i,a]+q[j,a]|
// masked softmax over j; PV (probs @ K) via bf16 MFMA, 8 waves = 4 i-quads
// x 2 a-quads of the 64x32 output.
// ---------------------------------------------------------------------------
__global__ __launch_bounds__(512, 1) void attn_kernel(
    const float* __restrict__ q, const float* __restrict__ k,
    const int* __restrict__ adj, const float* __restrict__ w_attn,
    float* __restrict__ vals) {
  __shared__ __align__(16) float Qt[A_][260];             // q^T fp32
  __shared__ __align__(16) __hip_bfloat16 KT[A_][264];    // k^T bf16
  __shared__ __align__(16) float Kr[64][36];              // k rows fp32
  __shared__ __align__(16) __hip_bfloat16 S[64][264];     // probs bf16
  __shared__ __align__(16) float wsh[A_];

  const int bh = blockIdx.x >> 2;  // 4 i-tiles of 64 rows
  const int it = blockIdx.x & 3;
  const int b = bh >> 3, h = bh & 7;
  const int t = threadIdx.x;

  const float4* qb4 = (const float4*)(q + bh * (L_ * A_));
  const float4* kb4 = (const float4*)(k + bh * (L_ * A_));
#pragma unroll
  for (int r = 0; r < 4; ++r) {
    int idx4 = r * 512 + t;  // 0..2047
    int j = idx4 >> 3, ab = idx4 & 7;
    float4 v = qb4[idx4];
    Qt[ab * 4 + 0][j] = v.x;
    Qt[ab * 4 + 1][j] = v.y;
    Qt[ab * 4 + 2][j] = v.z;
    Qt[ab * 4 + 3][j] = v.w;
    float4 u = kb4[idx4];
    KT[ab * 4 + 0][j] = __float2bfloat16(u.x);
    KT[ab * 4 + 1][j] = __float2bfloat16(u.y);
    KT[ab * 4 + 2][j] = __float2bfloat16(u.z);
    KT[ab * 4 + 3][j] = __float2bfloat16(u.w);
  }
  {
    const float4* kr4g = (const float4*)(k + bh * (L_ * A_) + it * 64 * A_);
    int ii = t >> 3, ab = t & 7;  // 512 threads: 64 rows x 8 quads
    float4 v = kr4g[t];
    Kr[ii][ab * 4 + 0] = v.x;
    Kr[ii][ab * 4 + 1] = v.y;
    Kr[ii][ab * 4 + 2] = v.z;
    Kr[ii][ab * 4 + 3] = v.w;
  }
  if (t < A_) wsh[t] = w_attn[t];
  __syncthreads();

  const int wave = t >> 6, lane = t & 63;
  const int w8 = wave * 8;
  const int i0 = it * 64 + w8;
  const int* adjb = adj + b * (L_ * L_);

  int adjv[8][4];
#pragma unroll
  for (int r = 0; r < 8; ++r)
#pragma unroll
    for (int c = 0; c < 4; ++c)
      adjv[r][c] = adjb[(i0 + r) * L_ + c * 64 + lane];

  float p[8][4] = {};
  float ck[8] = {};
  float cq[4] = {};
#pragma unroll 2
  for (int ab = 0; ab < 8; ++ab) {
    float4 wv = *(const float4*)&wsh[ab * 4];
    float4 kr4[8];
#pragma unroll
    for (int r = 0; r < 8; ++r)
      kr4[r] = *(const float4*)&Kr[w8 + r][ab * 4];
#pragma unroll
    for (int r = 0; r < 8; ++r) {
      ck[r] = fmaf(wv.x, kr4[r].x, ck[r]);
      ck[r] = fmaf(wv.y, kr4[r].y, ck[r]);
      ck[r] = fmaf(wv.z, kr4[r].z, ck[r]);
      ck[r] = fmaf(wv.w, kr4[r].w, ck[r]);
    }
#pragma unroll
    for (int c = 0; c < 4; ++c) {
      const int j = c * 64 + lane;
      float q0 = Qt[ab * 4 + 0][j];
      float q1 = Qt[ab * 4 + 1][j];
      float q2 = Qt[ab * 4 + 2][j];
      float q3 = Qt[ab * 4 + 3][j];
      cq[c] = fmaf(wv.x, q0, cq[c]);
      cq[c] = fmaf(wv.y, q1, cq[c]);
      cq[c] = fmaf(wv.z, q2, cq[c]);
      cq[c] = fmaf(wv.w, q3, cq[c]);
#pragma unroll
      for (int r = 0; r < 8; ++r) {
        p[r][c] = fmaf(wv.x, fabsf(kr4[r].x + q0), p[r][c]);
        p[r][c] = fmaf(wv.y, fabsf(kr4[r].y + q1), p[r][c]);
        p[r][c] = fmaf(wv.z, fabsf(kr4[r].z + q2), p[r][c]);
        p[r][c] = fmaf(wv.w, fabsf(kr4[r].w + q3), p[r][c]);
      }
    }
  }

#pragma unroll
  for (int r = 0; r < 8; ++r) {
    float s[4];
    float m = -3.0e38f;
#pragma unroll
    for (int c = 0; c < 4; ++c) {
      float sc = fmaf(0.4f, p[r][c], 0.6f * (ck[r] + cq[c]));
      s[c] = adjv[r][c] ? sc : -3.0e38f;
      m = fmaxf(m, s[c]);
    }
#pragma unroll
    for (int off = 32; off >= 1; off >>= 1) m = fmaxf(m, __shfl_xor(m, off));
    float sum = 0.f;
#pragma unroll
    for (int c = 0; c < 4; ++c) {
      s[c] = __expf(s[c] - m);
      sum += s[c];
    }
#pragma unroll
    for (int off = 32; off >= 1; off >>= 1) sum += __shfl_xor(sum, off);
    float inv = 1.0f / sum;
#pragma unroll
    for (int c = 0; c < 4; ++c)
      S[w8 + r][c * 64 + lane] = __float2bfloat16(s[c] * inv);
  }
  __syncthreads();

  // PV: 8 waves = 4 i-quadrants x 2 a-quadrants of the 64x32 output
  const int mi = wave >> 1;
  const int ai = wave & 1;
  const int fr = lane & 15;
  const int fk = (lane >> 4) * 8;
  f32x4 acc = {0.f, 0.f, 0.f, 0.f};
#pragma unroll
  for (int kt = 0; kt < 8; ++kt) {
    bf16x8 afrag = *(const bf16x8*)&S[mi * 16 + fr][kt * 32 + fk];
    bf16x8 bfrag = *(const bf16x8*)&KT[ai * 16 + fr][kt * 32 + fk];
    acc = __builtin_amdgcn_mfma_f32_16x16x32_bf16(afrag, bfrag, acc, 0, 0, 0);
  }
  const int arow = ai * 16 + fr;
  const int rbase = mi * 16 + ((lane >> 4) << 2);
#pragma unroll
  for (int g = 0; g < 4; ++g) {
    int i = it * 64 + rbase + g;
    vals[(b * L_ + i) * E_ + h * A_ + arow] = acc[g];
  }
}

extern "C" void kernel_launch(void* const* d_in, const int* in_sizes, int n_in,
                              void* d_out, int out_size, void* d_ws,
                              size_t ws_size, hipStream_t stream) {
  const float* emb = (const float*)d_in[0];
  const int* adj = (const int*)d_in[1];
  const float* W_qk = (const float*)d_in[2];
  const float* w_attn = (const float*)d_in[3];
  const float* W_out = (const float*)d_in[4];
  float* out = (float*)d_out;

  float* q = (float*)d_ws;
  float* k = q + B_ * H_ * L_ * A_;
  float* vals = k + B_ * H_ * L_ * A_;

  // qk = emb @ W_qk^T -> q,k   (M=2048, N=512)
  gemm_mfma<1><<<dim3(32 * 8), 256, 0, stream>>>(emb, W_qk, q, k, 512);
  // attention (64 bh x 4 i-tiles of 64 rows)
  attn_kernel<<<dim3(256), 512, 0, stream>>>(q, k, adj, w_attn, vals);
  // out = vals @ W_out^T      (M=2048, N=256)
  gemm_mfma<0><<<dim3(32 * 4), 256, 0, stream>>>(vals, W_out, out, nullptr,
                                                 256);
}